// Round 2
// baseline (2586.607 us; speedup 1.0000x reference)
//
#include <hip/hip_runtime.h>
#include <cfloat>

#define NV    1024
#define CDIM  256
#define NROWS 131072
#define TOTAL 33554432
#define HW    4096

// ---------------------------------------------------------------------------
// Bitwise replication of numpy float32 pairwise sum of 256 contiguous terms
// (AVX512 universal-intrinsics base case):
//   n=256 -> recurse: S128(a) + S128(a+128)
//   S128: sum0..3 = a[0:16],a[16:32],a[32:48],a[48:64]; one accumulate pass
//         adds a[64:128); t = (s0+s1)+(s2+s3); horizontal tree strides 8,4,2,1.
// GET(c) must return the fp32 term (already rounded, e.g. __fmul_rn(v,v)).
// ---------------------------------------------------------------------------
template <typename GET>
__device__ __forceinline__ float np_s128(const GET& get, int base) {
    float tv[16];
#pragma unroll
    for (int l = 0; l < 16; ++l) {
        float s0 = __fadd_rn(get(base + l),      get(base + 64 + l));
        float s1 = __fadd_rn(get(base + 16 + l), get(base + 80 + l));
        float s2 = __fadd_rn(get(base + 32 + l), get(base + 96 + l));
        float s3 = __fadd_rn(get(base + 48 + l), get(base + 112 + l));
        tv[l] = __fadd_rn(__fadd_rn(s0, s1), __fadd_rn(s2, s3));
    }
    float u[8];
#pragma unroll
    for (int l = 0; l < 8; ++l) u[l] = __fadd_rn(tv[l], tv[l + 8]);
    float v[4];
#pragma unroll
    for (int l = 0; l < 4; ++l) v[l] = __fadd_rn(u[l], u[l + 4]);
    float w0 = __fadd_rn(v[0], v[2]);
    float w1 = __fadd_rn(v[1], v[3]);
    return __fadd_rn(w0, w1);
}

template <typename GET>
__device__ __forceinline__ float np_s256(const GET& get) {
    return __fadd_rn(np_s128(get, 0), np_s128(get, 128));
}

__global__ void zero_hdr(double* loss) {
    if (threadIdx.x == 0) { *loss = 0.0; }
}

// ||e_k||^2 in numpy-fp32-pairwise order.
__global__ void enorm_kernel(const float* __restrict__ emb, float* __restrict__ enf) {
    int k = blockIdx.x * blockDim.x + threadIdx.x;
    if (k < NV) {
        const float* e = emb + (size_t)k * CDIM;
        auto get = [e](int c) { return __fmul_rn(e[c], e[c]); };
        enf[k] = np_s256(get);
    }
}

// Argmin over d32[k] = fl( fl(s_x + s_e[k]) - fl(2 * (x . e_k)) ),
// dot = sequential ascending-c fp32 FMA (OpenBLAS sgemm micro-kernel order).
// Block = 256 thr (4 waves), 64 rows/block; wave q owns k in [q*256,(q+1)*256).
__global__ __launch_bounds__(256) void argmin_kernel(
        const float* __restrict__ x, const float* __restrict__ emb,
        const float* __restrict__ enf, int* __restrict__ idx) {
    __shared__ float sx[CDIM][64];
    __shared__ float sv1[4][64];
    __shared__ int   si[4][64];

    const int tid = threadIdx.x;
    const int rowbase = blockIdx.x * 64;
    const int b   = rowbase >> 12;      // /4096 (64-row tile never crosses b)
    const int hw0 = rowbase & 4095;

    // Stage x tile: sx[c][p] = xf[rowbase+p][c]
    const float* xb = x + ((size_t)b * CDIM) * HW + hw0;
    for (int i = tid; i < CDIM * 64; i += 256) {
        int c = i >> 6, p = i & 63;
        sx[c][p] = xb[(size_t)c * HW + p];
    }
    __syncthreads();

    const int p = tid & 63;
    const int q = __builtin_amdgcn_readfirstlane(tid >> 6);   // wave-uniform

    // s_x for this lane's row, numpy pairwise order (redundant per wave - cheap)
    float sxn;
    {
        auto get = [&](int c) { float v = sx[c][p]; return __fmul_rn(v, v); };
        sxn = np_s256(get);
    }

    float m1 = FLT_MAX;
    int   mi = 0;

    for (int g = 0; g < 16; ++g) {
        const int kb = q * 256 + g * 16;                       // uniform
        const float* eb = emb + (size_t)kb * CDIM;             // scalar base
        float acc[16];
#pragma unroll
        for (int j = 0; j < 16; ++j) acc[j] = 0.f;
        for (int c = 0; c < CDIM; ++c) {
            float xv = sx[c][p];
#pragma unroll
            for (int j = 0; j < 16; ++j)
                acc[j] = __fmaf_rn(xv, eb[(size_t)j * CDIM + c], acc[j]);
        }
#pragma unroll
        for (int j = 0; j < 16; ++j) {
            float T = __fadd_rn(sxn, enf[kb + j]);             // fl(s_x + s_e)
            float d = __fsub_rn(T, __fmul_rn(2.0f, acc[j]));   // fl(T - 2g)
            if (d < m1) { m1 = d; mi = kb + j; }               // first-min ties
        }
    }

    sv1[q][p] = m1; si[q][p] = mi;
    __syncthreads();

    // Merge 4 wave-candidates (ascending wave = ascending k; strict < keeps
    // lowest k on bitwise-equal d -> np.argmin semantics).
    if (tid < 64) {
        float M1 = FLT_MAX; int MI = 0;
#pragma unroll
        for (int w = 0; w < 4; ++w) {
            float v1 = sv1[w][tid];
            if (v1 < M1) { M1 = v1; MI = si[w][tid]; }
        }
        idx[rowbase + tid] = MI;
    }
}

// Gather x_q = emb[idx] in [B,C,H,W] order + accumulate sum((x_q-x)^2) fp64.
__global__ __launch_bounds__(256) void gather_kernel(
        const float* __restrict__ x, const float* __restrict__ emb,
        const int* __restrict__ idx, float* __restrict__ out,
        double* __restrict__ loss) {
    __shared__ double red[256];
    const size_t stride = (size_t)gridDim.x * blockDim.x;
    double s = 0.0;
    for (size_t g = (size_t)blockIdx.x * blockDim.x + threadIdx.x;
         g < (size_t)TOTAL; g += stride) {
        int c = (int)((g >> 12) & 255);
        int r = (int)(((g >> 20) << 12) | (g & 4095));
        float ev = emb[(size_t)idx[r] * CDIM + c];
        float xv = x[g];
        out[g] = ev;
        float d = ev - xv;
        s = fma((double)d, (double)d, s);
    }
    red[threadIdx.x] = s;
    __syncthreads();
    for (int sft = 128; sft > 0; sft >>= 1) {
        if (threadIdx.x < sft) red[threadIdx.x] += red[threadIdx.x + sft];
        __syncthreads();
    }
    if (threadIdx.x == 0) atomicAdd(loss, red[0]);
}

__global__ void idxout_kernel(const int* __restrict__ idx, float* __restrict__ oidx) {
    int r = blockIdx.x * blockDim.x + threadIdx.x;
    if (r < NROWS) oidx[r] = (float)idx[r];
}

__global__ void fin_kernel(const double* __restrict__ loss, float* __restrict__ o) {
    // forward: loss = (1 + BETA) * mean((x_q - x)^2)
    *o = (float)(1.25 * (*loss) / (double)TOTAL);
}

extern "C" void kernel_launch(void* const* d_in, const int* in_sizes, int n_in,
                              void* d_out, int out_size, void* d_ws, size_t ws_size,
                              hipStream_t stream) {
    const float* x   = (const float*)d_in[0];
    const float* emb = (const float*)d_in[1];
    float* out = (float*)d_out;
    char*  ws  = (char*)d_ws;

    double* loss = (double*)ws;
    float*  enf  = (float*)(ws + 16);
    int*    idx  = (int*)(ws + 16 + 4096);

    float* out_xq   = out;
    float* out_idx  = out + (size_t)TOTAL;
    float* out_loss = out + (size_t)TOTAL + NROWS;

    hipLaunchKernelGGL(zero_hdr,      dim3(1),           dim3(64),  0, stream, loss);
    hipLaunchKernelGGL(enorm_kernel,  dim3(4),           dim3(256), 0, stream, emb, enf);
    hipLaunchKernelGGL(argmin_kernel, dim3(NROWS / 64),  dim3(256), 0, stream,
                       x, emb, enf, idx);
    hipLaunchKernelGGL(gather_kernel, dim3(8192),        dim3(256), 0, stream,
                       x, emb, idx, out_xq, loss);
    hipLaunchKernelGGL(idxout_kernel, dim3(NROWS / 256), dim3(256), 0, stream, idx, out_idx);
    hipLaunchKernelGGL(fin_kernel,    dim3(1),           dim3(1),   0, stream, loss, out_loss);
}

// Round 3
// 1626.803 us; speedup vs baseline: 1.5900x; 1.5900x over previous
//
#include <hip/hip_runtime.h>
#include <cfloat>

#define NV    1024
#define CDIM  256
#define NROWS 131072
#define TOTAL 33554432
#define HW    4096

// ---------------------------------------------------------------------------
// Bitwise replication of numpy float32 pairwise sum of 256 contiguous terms
// (AVX512 universal-intrinsics base case). GET(c) returns the fp32 term.
// ---------------------------------------------------------------------------
template <typename GET>
__device__ __forceinline__ float np_s128(const GET& get, int base) {
    float tv[16];
#pragma unroll
    for (int l = 0; l < 16; ++l) {
        float s0 = __fadd_rn(get(base + l),      get(base + 64 + l));
        float s1 = __fadd_rn(get(base + 16 + l), get(base + 80 + l));
        float s2 = __fadd_rn(get(base + 32 + l), get(base + 96 + l));
        float s3 = __fadd_rn(get(base + 48 + l), get(base + 112 + l));
        tv[l] = __fadd_rn(__fadd_rn(s0, s1), __fadd_rn(s2, s3));
    }
    float u[8];
#pragma unroll
    for (int l = 0; l < 8; ++l) u[l] = __fadd_rn(tv[l], tv[l + 8]);
    float v[4];
#pragma unroll
    for (int l = 0; l < 4; ++l) v[l] = __fadd_rn(u[l], u[l + 4]);
    return __fadd_rn(__fadd_rn(v[0], v[2]), __fadd_rn(v[1], v[3]));
}

template <typename GET>
__device__ __forceinline__ float np_s256(const GET& get) {
    return __fadd_rn(np_s128(get, 0), np_s128(get, 128));
}

__global__ void zero_hdr(double* loss) {
    if (threadIdx.x == 0) { *loss = 0.0; }
}

__global__ void enorm_kernel(const float* __restrict__ emb, float* __restrict__ enf) {
    int k = blockIdx.x * blockDim.x + threadIdx.x;
    if (k < NV) {
        const float* e = emb + (size_t)k * CDIM;
        auto get = [e](int c) { return __fmul_rn(e[c], e[c]); };
        enf[k] = np_s256(get);
    }
}

// ---------------------------------------------------------------------------
// Register-blocked argmin. Block = 256 thr, 32 rows/block.
// thread: rowg = tid&7 -> rows {rowg, rowg+8, rowg+16, rowg+24} (R=4)
//         kg   = tid>>3 (0..31) -> 8 codes {pass*256 + kg*8 + j} per pass (J=8)
// 4 passes cover k=0..1023. Dot = sequential ascending-c fp32 FMA chain
// (bitwise np/OpenBLAS semantics preserved).
// LDS x-tile stride 260: 16B-aligned rows; same-instr lanes read rows
// rowg+8r -> bank step 4 -> conflict-free ds_read_b128.
// ---------------------------------------------------------------------------
#define RPB 32          // rows per block
#define XLD 260         // padded leading dim

__global__ __launch_bounds__(256, 3) void argmin_kernel(
        const float* __restrict__ x, const float* __restrict__ emb,
        const float* __restrict__ enf, int* __restrict__ idx) {
    __shared__ float sx[RPB][XLD];
    __shared__ float snorm[RPB];
    __shared__ float cd[32][RPB];
    __shared__ int   ck[32][RPB];

    const int tid = threadIdx.x;
    const int rowbase = blockIdx.x * RPB;
    const int b   = rowbase >> 12;          // /4096 (tile never crosses b)
    const int hw0 = rowbase & 4095;

    // Stage x tile: sx[p][c] = x[b][c][hw0+p], float4 along hw.
    const float* xb = x + ((size_t)b * CDIM) * HW + hw0;
    for (int i = tid; i < RPB * CDIM / 4; i += 256) {
        int c  = i >> 3;
        int p4 = (i & 7) * 4;
        float4 v = *(const float4*)(xb + (size_t)c * HW + p4);
        sx[p4 + 0][c] = v.x; sx[p4 + 1][c] = v.y;
        sx[p4 + 2][c] = v.z; sx[p4 + 3][c] = v.w;
    }
    __syncthreads();

    // Per-row ||x||^2, numpy pairwise order.
    if (tid < RPB) {
        const float* r = sx[tid];
        auto get = [r](int c) { float v = r[c]; return __fmul_rn(v, v); };
        snorm[tid] = np_s256(get);
    }
    __syncthreads();

    const int rowg = tid & 7;
    const int kg   = tid >> 3;

    float sxr[4];
#pragma unroll
    for (int r = 0; r < 4; ++r) sxr[r] = snorm[rowg + 8 * r];

    float m1[4]; int mi[4];
#pragma unroll
    for (int r = 0; r < 4; ++r) { m1[r] = FLT_MAX; mi[r] = 0x7fffffff; }

    for (int pass = 0; pass < 4; ++pass) {
        const int kt = pass * 256 + kg * 8;            // thread's first code
        const float* eb = emb + (size_t)kt * CDIM;

        float en[8];
#pragma unroll
        for (int j = 0; j < 8; ++j) en[j] = enf[kt + j];

        float acc[4][8];
#pragma unroll
        for (int r = 0; r < 4; ++r)
#pragma unroll
            for (int j = 0; j < 8; ++j) acc[r][j] = 0.f;

        // prefetch chunk c=0
        float4 xa[4], ea[8];
#pragma unroll
        for (int r = 0; r < 4; ++r)
            xa[r] = *(const float4*)&sx[rowg + 8 * r][0];
#pragma unroll
        for (int j = 0; j < 8; ++j)
            ea[j] = *(const float4*)(eb + (size_t)j * CDIM);

        for (int c = 0; c < CDIM - 4; c += 4) {
            float4 xn[4], enx[8];
#pragma unroll
            for (int r = 0; r < 4; ++r)
                xn[r] = *(const float4*)&sx[rowg + 8 * r][c + 4];
#pragma unroll
            for (int j = 0; j < 8; ++j)
                enx[j] = *(const float4*)(eb + (size_t)j * CDIM + c + 4);

#pragma unroll
            for (int r = 0; r < 4; ++r)
#pragma unroll
                for (int j = 0; j < 8; ++j) {
                    float a = acc[r][j];
                    a = __fmaf_rn(xa[r].x, ea[j].x, a);
                    a = __fmaf_rn(xa[r].y, ea[j].y, a);
                    a = __fmaf_rn(xa[r].z, ea[j].z, a);
                    a = __fmaf_rn(xa[r].w, ea[j].w, a);
                    acc[r][j] = a;
                }
#pragma unroll
            for (int r = 0; r < 4; ++r) xa[r] = xn[r];
#pragma unroll
            for (int j = 0; j < 8; ++j) ea[j] = enx[j];
        }
        // last chunk (c = 252)
#pragma unroll
        for (int r = 0; r < 4; ++r)
#pragma unroll
            for (int j = 0; j < 8; ++j) {
                float a = acc[r][j];
                a = __fmaf_rn(xa[r].x, ea[j].x, a);
                a = __fmaf_rn(xa[r].y, ea[j].y, a);
                a = __fmaf_rn(xa[r].z, ea[j].z, a);
                a = __fmaf_rn(xa[r].w, ea[j].w, a);
                acc[r][j] = a;
            }

        // d = fl( fl(sx + se) - fl(2*dot) ); first-min (ascending k) tie-break
#pragma unroll
        for (int r = 0; r < 4; ++r)
#pragma unroll
            for (int j = 0; j < 8; ++j) {
                float T = __fadd_rn(sxr[r], en[j]);
                float d = __fsub_rn(T, __fmul_rn(2.0f, acc[r][j]));
                if (d < m1[r]) { m1[r] = d; mi[r] = kt + j; }
            }
    }

#pragma unroll
    for (int r = 0; r < 4; ++r) {
        cd[kg][rowg + 8 * r] = m1[r];
        ck[kg][rowg + 8 * r] = mi[r];
    }
    __syncthreads();

    // Merge 32 kg-candidates per row; lexicographic (d, k) keeps np.argmin
    // first-min semantics across interleaved k-sets.
    if (tid < RPB) {
        float M = FLT_MAX; int MK = 0x7fffffff;
#pragma unroll
        for (int g = 0; g < 32; ++g) {
            float d = cd[g][tid]; int k = ck[g][tid];
            if (d < M || (d == M && k < MK)) { M = d; MK = k; }
        }
        idx[rowbase + tid] = MK;
    }
}

// Gather x_q = emb[idx] in [B,C,H,W] order + accumulate sum((x_q-x)^2) fp64.
__global__ __launch_bounds__(256) void gather_kernel(
        const float* __restrict__ x, const float* __restrict__ emb,
        const int* __restrict__ idx, float* __restrict__ out,
        double* __restrict__ loss) {
    __shared__ double red[256];
    const size_t stride = (size_t)gridDim.x * blockDim.x;
    double s = 0.0;
    for (size_t g = (size_t)blockIdx.x * blockDim.x + threadIdx.x;
         g < (size_t)TOTAL; g += stride) {
        int c = (int)((g >> 12) & 255);
        int r = (int)(((g >> 20) << 12) | (g & 4095));
        float ev = emb[(size_t)idx[r] * CDIM + c];
        float xv = x[g];
        out[g] = ev;
        float d = ev - xv;
        s = fma((double)d, (double)d, s);
    }
    red[threadIdx.x] = s;
    __syncthreads();
    for (int sft = 128; sft > 0; sft >>= 1) {
        if (threadIdx.x < sft) red[threadIdx.x] += red[threadIdx.x + sft];
        __syncthreads();
    }
    if (threadIdx.x == 0) atomicAdd(loss, red[0]);
}

__global__ void idxout_kernel(const int* __restrict__ idx, float* __restrict__ oidx) {
    int r = blockIdx.x * blockDim.x + threadIdx.x;
    if (r < NROWS) oidx[r] = (float)idx[r];
}

__global__ void fin_kernel(const double* __restrict__ loss, float* __restrict__ o) {
    *o = (float)(1.25 * (*loss) / (double)TOTAL);
}

extern "C" void kernel_launch(void* const* d_in, const int* in_sizes, int n_in,
                              void* d_out, int out_size, void* d_ws, size_t ws_size,
                              hipStream_t stream) {
    const float* x   = (const float*)d_in[0];
    const float* emb = (const float*)d_in[1];
    float* out = (float*)d_out;
    char*  ws  = (char*)d_ws;

    double* loss = (double*)ws;
    float*  enf  = (float*)(ws + 16);
    int*    idx  = (int*)(ws + 16 + 4096);

    float* out_xq   = out;
    float* out_idx  = out + (size_t)TOTAL;
    float* out_loss = out + (size_t)TOTAL + NROWS;

    hipLaunchKernelGGL(zero_hdr,      dim3(1),            dim3(64),  0, stream, loss);
    hipLaunchKernelGGL(enorm_kernel,  dim3(4),            dim3(256), 0, stream, emb, enf);
    hipLaunchKernelGGL(argmin_kernel, dim3(NROWS / RPB),  dim3(256), 0, stream,
                       x, emb, enf, idx);
    hipLaunchKernelGGL(gather_kernel, dim3(8192),         dim3(256), 0, stream,
                       x, emb, idx, out_xq, loss);
    hipLaunchKernelGGL(idxout_kernel, dim3(NROWS / 256),  dim3(256), 0, stream, idx, out_idx);
    hipLaunchKernelGGL(fin_kernel,    dim3(1),            dim3(1),   0, stream, loss, out_loss);
}

// Round 5
// 1008.085 us; speedup vs baseline: 2.5659x; 1.6138x over previous
//
#include <hip/hip_runtime.h>
#include <cfloat>

#define NV    1024
#define CDIM  256
#define NROWS 131072
#define TOTAL 33554432
#define HW    4096
#define WWIN  1.5e-4f      // candidate window: np-fp32 quant swing (<=6.5e-5) + margin

typedef __attribute__((ext_vector_type(8))) short bf16x8;
typedef __attribute__((ext_vector_type(4))) float f32x4;

// ---------------------------------------------------------------------------
// numpy fp32 pairwise sum of 256 terms (AVX512 base case) — bitwise replica.
// ---------------------------------------------------------------------------
template <typename GET>
__device__ __forceinline__ float np_s128(const GET& get, int base) {
    float tv[16];
#pragma unroll
    for (int l = 0; l < 16; ++l) {
        float s0 = __fadd_rn(get(base + l),      get(base + 64 + l));
        float s1 = __fadd_rn(get(base + 16 + l), get(base + 80 + l));
        float s2 = __fadd_rn(get(base + 32 + l), get(base + 96 + l));
        float s3 = __fadd_rn(get(base + 48 + l), get(base + 112 + l));
        tv[l] = __fadd_rn(__fadd_rn(s0, s1), __fadd_rn(s2, s3));
    }
    float u[8];
#pragma unroll
    for (int l = 0; l < 8; ++l) u[l] = __fadd_rn(tv[l], tv[l + 8]);
    float v[4];
#pragma unroll
    for (int l = 0; l < 4; ++l) v[l] = __fadd_rn(u[l], u[l + 4]);
    return __fadd_rn(__fadd_rn(v[0], v[2]), __fadd_rn(v[1], v[3]));
}
template <typename GET>
__device__ __forceinline__ float np_s256(const GET& get) {
    return __fadd_rn(np_s128(get, 0), np_s128(get, 128));
}

__device__ __forceinline__ unsigned short f2bf_rne(float f) {
    unsigned u = __float_as_uint(f);
    unsigned r = u + 0x7fffu + ((u >> 16) & 1u);
    return (unsigned short)(r >> 16);
}
__device__ __forceinline__ float bf2f(unsigned short h) {
    return __uint_as_float(((unsigned)h) << 16);
}

// exact np-fp32 distance: d = fl( fl(sx+se) - fl(2 * seqFMA(x,e)) )
__device__ __forceinline__ float exact_d(const float* __restrict__ xrow,
                                         const float* __restrict__ erow,
                                         float sxn, float se) {
    float g = 0.f;
    for (int c = 0; c < CDIM; ++c) g = __fmaf_rn(xrow[c], erow[c], g);
    return __fsub_rn(__fadd_rn(sxn, se), __fmul_rn(2.0f, g));
}

__global__ void zero_hdr(double* loss, int* fbcnt) {
    if (threadIdx.x == 0) { *loss = 0.0; *fbcnt = 0; }
}

__global__ void enorm_kernel(const float* __restrict__ emb, float* __restrict__ enf) {
    int k = blockIdx.x * blockDim.x + threadIdx.x;
    if (k < NV) {
        const float* e = emb + (size_t)k * CDIM;
        auto get = [e](int c) { return __fmul_rn(e[c], e[c]); };
        enf[k] = np_s256(get);
    }
}

// split emb into bf16 hi/lo (RNE)
__global__ void esplit_kernel(const float* __restrict__ emb,
                              unsigned short* __restrict__ ehg,
                              unsigned short* __restrict__ elg) {
    int i = blockIdx.x * blockDim.x + threadIdx.x;
    if (i < NV * CDIM) {
        float e = emb[i];
        unsigned short h = f2bf_rne(e);
        unsigned short l = f2bf_rne(__fsub_rn(e, bf2f(h)));
        ehg[i] = h; elg[i] = l;
    }
}

// ---------------------------------------------------------------------------
// MFMA argmin: block 256 thr (4 waves, 2x2), M-tile 64 rows, N chunks of 64.
// A (x splits) in registers, B (e splits) staged in swizzled LDS.
// acc = xh*eh + xh*el + xl*eh  (approx z within ~1e-6 of np-fp32 z)
// Candidate window WWIN -> inline exact np-fp32 re-eval; same-slot doubles
// -> fallback full-scan kernel.
// ---------------------------------------------------------------------------
#define XLD 264

__global__ __launch_bounds__(256, 1) void gemm_argmin_kernel(
        const float* __restrict__ x, const float* __restrict__ emb,
        const unsigned short* __restrict__ ehg, const unsigned short* __restrict__ elg,
        const float* __restrict__ enf, int* __restrict__ idx,
        int* __restrict__ fb_list, int* __restrict__ fb_cnt) {
    __shared__ float sx[64][XLD];            // fp32 x tile  (67.6 KB)
    __shared__ unsigned short sBh[64 * 256]; // eh chunk, swizzled (32 KB)
    __shared__ unsigned short sBl[64 * 256]; // el chunk, swizzled (32 KB)
    __shared__ float sxn[64];

    const int tid  = threadIdx.x;
    const int lane = tid & 63;
    const int lcol = lane & 15;
    const int quad = lane >> 4;
    const int wid  = tid >> 6;
    const int wy   = wid >> 1;               // m-half
    const int wx   = wid & 1;                // n-half
    const int mbase = wy * 32;

    const int rowbase = blockIdx.x * 64;
    const int b   = rowbase >> 12;
    const int hw0 = rowbase & 4095;
    const float* xb = x + ((size_t)b * CDIM) * HW + hw0;

    // ---- stage x tile (fp32): 16 iters x 256 thr x float4 ----
    for (int it = 0; it < 16; ++it) {
        int c  = it * 16 + (tid >> 4);
        int m4 = (tid & 15) * 4;
        float4 v = *(const float4*)(xb + (size_t)c * HW + m4);
        sx[m4 + 0][c] = v.x; sx[m4 + 1][c] = v.y;
        sx[m4 + 2][c] = v.z; sx[m4 + 3][c] = v.w;
    }
    __syncthreads();

    if (tid < 64) {
        const float* r = sx[tid];
        auto get = [r](int c) { float v = r[c]; return __fmul_rn(v, v); };
        sxn[tid] = np_s256(get);
    }

    // ---- build A fragments in registers: ah/al[mtile][kchunk] ----
    bf16x8 ah[2][8], al[2][8];
#pragma unroll
    for (int t = 0; t < 2; ++t) {
        const int m = mbase + t * 16 + lcol;
#pragma unroll
        for (int kc = 0; kc < 8; ++kc) {
            const int c0 = kc * 32 + quad * 8;
            float4 f0 = *(const float4*)&sx[m][c0];
            float4 f1 = *(const float4*)&sx[m][c0 + 4];
            float fv[8] = {f0.x, f0.y, f0.z, f0.w, f1.x, f1.y, f1.z, f1.w};
#pragma unroll
            for (int j = 0; j < 8; ++j) {
                unsigned short h = f2bf_rne(fv[j]);
                unsigned short l = f2bf_rne(__fsub_rn(fv[j], bf2f(h)));
                ah[t][kc][j] = (short)h;
                al[t][kc][j] = (short)l;
            }
        }
    }

    // ---- per-lane min tracking: 8 slots (2 mtiles x 4 regs) ----
    float m1[8], m2[8]; int i1[8];
#pragma unroll
    for (int s = 0; s < 8; ++s) { m1[s] = FLT_MAX; m2[s] = FLT_MAX; i1[s] = 0x7fffffff; }

    for (int ch = 0; ch < 16; ++ch) {
        const int k0 = ch * 64;
        __syncthreads();
        // stage B chunk (swizzled: 8-elem group s stored at column-group (s+n)&31)
        for (int it = 0; it < 8; ++it) {
            int n = (tid >> 5) + it * 8;
            int s = tid & 31;
            int src = (k0 + n) * 256 + s * 8;
            int dst = n * 256 + (((s + n) & 31) * 8);
            *(uint4*)&sBh[dst] = *(const uint4*)&ehg[src];
            *(uint4*)&sBl[dst] = *(const uint4*)&elg[src];
        }
        __syncthreads();

        float enfv[2];
#pragma unroll
        for (int u = 0; u < 2; ++u)
            enfv[u] = enf[k0 + wx * 32 + u * 16 + lcol];

        f32x4 acc[2][2];
#pragma unroll
        for (int t = 0; t < 2; ++t)
#pragma unroll
            for (int u = 0; u < 2; ++u) acc[t][u] = (f32x4){0.f, 0.f, 0.f, 0.f};

#pragma unroll
        for (int kc = 0; kc < 8; ++kc) {
            bf16x8 bh[2], bl[2];
#pragma unroll
            for (int u = 0; u < 2; ++u) {
                int n_loc = wx * 32 + u * 16 + lcol;
                int s = kc * 4 + quad;
                int off = n_loc * 256 + (((s + n_loc) & 31) * 8);
                bh[u] = *(const bf16x8*)&sBh[off];
                bl[u] = *(const bf16x8*)&sBl[off];
            }
#pragma unroll
            for (int t = 0; t < 2; ++t)
#pragma unroll
                for (int u = 0; u < 2; ++u) {
                    acc[t][u] = __builtin_amdgcn_mfma_f32_16x16x32_bf16(
                        ah[t][kc], bh[u], acc[t][u], 0, 0, 0);
                    acc[t][u] = __builtin_amdgcn_mfma_f32_16x16x32_bf16(
                        ah[t][kc], bl[u], acc[t][u], 0, 0, 0);
                    acc[t][u] = __builtin_amdgcn_mfma_f32_16x16x32_bf16(
                        al[t][kc], bh[u], acc[t][u], 0, 0, 0);
                }
        }

        // chunk epilogue: z = enf - 2*ghat; update min1/min2 per slot
#pragma unroll
        for (int t = 0; t < 2; ++t)
#pragma unroll
            for (int u = 0; u < 2; ++u) {
                int k = k0 + wx * 32 + u * 16 + lcol;
#pragma unroll
                for (int r = 0; r < 4; ++r) {
                    float z = __fmaf_rn(-2.0f, acc[t][u][r], enfv[u]);
                    int s = t * 4 + r;
                    if (z < m1[s])      { m2[s] = m1[s]; m1[s] = z; i1[s] = k; }
                    else if (z < m2[s]) { m2[s] = z; }
                }
            }
    }
    __syncthreads();

    // ---- merge via reused B LDS ----
    // Mv1: sBh bytes [0, 8192)   Mi1: sBh bytes [8192, 16384)  (sBh is 32768 B)
    // Mv2: sBl bytes [0, 8192)   — no aliasing (round-4 bug: Mi1 was at byte
    // 32768 = sBl = Mv2, giving garbage candidate ks -> OOB reads -> abort).
    float* Mv1 = (float*)sBh;
    int*   Mi1 = (int*)((char*)sBh + 8192);
    float* Mv2 = (float*)sBl;
    const int col = wx * 16 + lcol;
#pragma unroll
    for (int t = 0; t < 2; ++t)
#pragma unroll
        for (int r = 0; r < 4; ++r) {
            int row = mbase + t * 16 + quad * 4 + r;
            int s = t * 4 + r;
            Mv1[row * 32 + col] = m1[s];
            Mi1[row * 32 + col] = i1[s];
            Mv2[row * 32 + col] = m2[s];
        }
    __syncthreads();

    if (tid < 64) {
        const int row = tid;
        float M = FLT_MAX;
        for (int c = 0; c < 32; ++c) M = fminf(M, Mv1[row * 32 + c]);
        const float lim = M + WWIN;

        int cand[8]; int cnt = 0; bool overflow = false;
        for (int c = 0; c < 32; ++c) {
            if (Mv2[row * 32 + c] <= lim) overflow = true;
            if (Mv1[row * 32 + c] <= lim) {
                if (cnt < 8) cand[cnt++] = Mi1[row * 32 + c] & (NV - 1); // defensive mask
                else overflow = true;
            }
        }
        if (overflow) {
            int pos = atomicAdd(fb_cnt, 1);
            fb_list[pos] = rowbase + row;
        } else if (cnt == 1) {
            idx[rowbase + row] = cand[0];
        } else {
            float bd = FLT_MAX; int bk = 0x7fffffff;
            for (int c = 0; c < cnt; ++c) {
                int k = cand[c];
                float d = exact_d(sx[row], emb + (size_t)k * CDIM, sxn[row], enf[k]);
                if (d < bd || (d == bd && k < bk)) { bd = d; bk = k; }
            }
            idx[rowbase + row] = bk;
        }
    }
}

// full exact scan for rare ambiguous rows: one block per row.
__global__ __launch_bounds__(256) void fallback_kernel(
        const float* __restrict__ x, const float* __restrict__ emb,
        const float* __restrict__ enf, int* __restrict__ idx,
        const int* __restrict__ fb_list, const int* __restrict__ fb_cnt) {
    __shared__ float sxr[CDIM];
    __shared__ float rv[256];
    __shared__ int   rk[256];

    const int n = *fb_cnt;
    for (int i = blockIdx.x; i < n; i += gridDim.x) {
        const int r  = fb_list[i];
        const int b  = r >> 12;
        const int hw = r & 4095;
        sxr[threadIdx.x] = x[((size_t)(b * CDIM + threadIdx.x)) * HW + hw];
        __syncthreads();

        auto get = [](int c) { float v = ((const float*)sxr)[c]; return __fmul_rn(v, v); };
        float sxn = np_s256(get);

        float bd = FLT_MAX; int bk = 0x7fffffff;
#pragma unroll
        for (int j = 0; j < 4; ++j) {
            const int k = threadIdx.x * 4 + j;
            float d = exact_d(sxr, emb + (size_t)k * CDIM, sxn, enf[k]);
            if (d < bd) { bd = d; bk = k; }    // ascending k per thread
        }
        rv[threadIdx.x] = bd; rk[threadIdx.x] = bk;
        __syncthreads();
        for (int sft = 128; sft > 0; sft >>= 1) {
            if (threadIdx.x < sft) {
                float ov = rv[threadIdx.x + sft]; int ok = rk[threadIdx.x + sft];
                if (ov < rv[threadIdx.x] ||
                    (ov == rv[threadIdx.x] && ok < rk[threadIdx.x])) {
                    rv[threadIdx.x] = ov; rk[threadIdx.x] = ok;
                }
            }
            __syncthreads();
        }
        if (threadIdx.x == 0) idx[r] = rk[0];
        __syncthreads();
    }
}

// coalesced gather: block = 64 rows; stage emb[idx] rows in LDS, write [c][hw].
__global__ __launch_bounds__(256) void gather_kernel(
        const float* __restrict__ x, const float* __restrict__ emb,
        const int* __restrict__ idx, float* __restrict__ out,
        double* __restrict__ loss) {
    __shared__ float sE[64][260];
    __shared__ int   sidx[64];
    __shared__ double red[256];

    const int tid = threadIdx.x;
    const int rowbase = blockIdx.x * 64;
    const int b   = rowbase >> 12;
    const int hw0 = rowbase & 4095;

    if (tid < 64) sidx[tid] = idx[rowbase + tid];
    __syncthreads();

    {
        const int r  = tid >> 2;
        const int qt = tid & 3;
        const float* e = emb + (size_t)sidx[r] * CDIM + qt * 64;
        for (int u = 0; u < 16; ++u) {
            float4 v = *(const float4*)(e + u * 4);
            *(float4*)&sE[r][qt * 64 + u * 4] = v;
        }
    }
    __syncthreads();

    const float* xb = x + ((size_t)b * CDIM) * HW + hw0;
    float* ob = out + ((size_t)b * CDIM) * HW + hw0;
    double s = 0.0;
    for (int it = 0; it < 16; ++it) {
        int c  = it * 16 + (tid >> 4);
        int m4 = (tid & 15) * 4;
        float4 ev;
        ev.x = sE[m4 + 0][c]; ev.y = sE[m4 + 1][c];
        ev.z = sE[m4 + 2][c]; ev.w = sE[m4 + 3][c];
        float4 xv = *(const float4*)(xb + (size_t)c * HW + m4);
        *(float4*)(ob + (size_t)c * HW + m4) = ev;
        float d0 = ev.x - xv.x, d1 = ev.y - xv.y, d2 = ev.z - xv.z, d3 = ev.w - xv.w;
        s = fma((double)d0, (double)d0, s);
        s = fma((double)d1, (double)d1, s);
        s = fma((double)d2, (double)d2, s);
        s = fma((double)d3, (double)d3, s);
    }
    red[tid] = s;
    __syncthreads();
    for (int sft = 128; sft > 0; sft >>= 1) {
        if (tid < sft) red[tid] += red[tid + sft];
        __syncthreads();
    }
    if (tid == 0) atomicAdd(loss, red[0]);
}

__global__ void idxout_kernel(const int* __restrict__ idx, float* __restrict__ oidx) {
    int r = blockIdx.x * blockDim.x + threadIdx.x;
    if (r < NROWS) oidx[r] = (float)idx[r];
}

__global__ void fin_kernel(const double* __restrict__ loss, float* __restrict__ o) {
    *o = (float)(1.25 * (*loss) / (double)TOTAL);
}

extern "C" void kernel_launch(void* const* d_in, const int* in_sizes, int n_in,
                              void* d_out, int out_size, void* d_ws, size_t ws_size,
                              hipStream_t stream) {
    const float* x   = (const float*)d_in[0];
    const float* emb = (const float*)d_in[1];
    float* out = (float*)d_out;
    char*  ws  = (char*)d_ws;

    double* loss    = (double*)ws;
    int*    fb_cnt  = (int*)(ws + 8);
    float*  enf     = (float*)(ws + 64);
    int*    idx     = (int*)(ws + 64 + 4096);
    int*    fb_list = idx + NROWS;

    unsigned short* ehg = (unsigned short*)d_out;   // scratch, overwritten by gather
    unsigned short* elg = ehg + NV * CDIM;

    float* out_xq   = out;
    float* out_idx  = out + (size_t)TOTAL;
    float* out_loss = out + (size_t)TOTAL + NROWS;

    hipLaunchKernelGGL(zero_hdr,         dim3(1),            dim3(64),  0, stream, loss, fb_cnt);
    hipLaunchKernelGGL(enorm_kernel,     dim3(4),            dim3(256), 0, stream, emb, enf);
    hipLaunchKernelGGL(esplit_kernel,    dim3(NV * CDIM / 256), dim3(256), 0, stream, emb, ehg, elg);
    hipLaunchKernelGGL(gemm_argmin_kernel, dim3(NROWS / 64), dim3(256), 0, stream,
                       x, emb, ehg, elg, enf, idx, fb_list, fb_cnt);
    hipLaunchKernelGGL(fallback_kernel,  dim3(256),          dim3(256), 0, stream,
                       x, emb, enf, idx, fb_list, fb_cnt);
    hipLaunchKernelGGL(gather_kernel,    dim3(NROWS / 64),   dim3(256), 0, stream,
                       x, emb, idx, out_xq, loss);
    hipLaunchKernelGGL(idxout_kernel,    dim3(NROWS / 256),  dim3(256), 0, stream, idx, out_idx);
    hipLaunchKernelGGL(fin_kernel,       dim3(1),            dim3(1),   0, stream, loss, out_loss);
}